// Round 3
// baseline (1976.757 us; speedup 1.0000x reference)
//
#include <hip/hip_runtime.h>
#include <stdint.h>

#define NN 2304        // nodes
#define NF 32          // frames
#define NB 1024        // batch
#define NS 256         // selected anchors

#define BM 128
#define BN 96
#define BK 64
#define KSLICES (NN / BK)   // 36
#define DEPTH 4             // slices in flight
#define NBUF 5              // LDS ring buffers (> DEPTH: enables single-barrier slice)
#define NGRP 8              // M-tile groups (== XCDs via id&7 swizzle)
#define GRPBLKS 24          // blocks per group (N tiles)

typedef short bf16x8 __attribute__((ext_vector_type(8)));
typedef float f32x4  __attribute__((ext_vector_type(4)));

__device__ __forceinline__ unsigned short f2bf(float f) {
  union { float f; unsigned u; } v; v.f = f;
  return (unsigned short)((v.u + 0x7FFFu + ((v.u >> 16) & 1u)) >> 16);  // RNE
}

__device__ __forceinline__ void async16(const void* g, void* l) {
  __builtin_amdgcn_global_load_lds((const __attribute__((address_space(1))) void*)g,
                                   (__attribute__((address_space(3))) void*)l, 16, 0, 0);
}

#define WAITV(n) asm volatile("s_waitcnt vmcnt(" #n ")" ::: "memory")

// ---------------------------------------------------------------------------
// init kernels (split + named so the profile attributes their cost)
// ---------------------------------------------------------------------------
__global__ void convert_w(const f32x4* __restrict__ W4, bf16x8* __restrict__ Wb8) {
  const int total = (31 * NN * NN) / 8;
  for (int gid = blockIdx.x * 256 + threadIdx.x; gid < total; gid += gridDim.x * 256) {
    f32x4 x = W4[2 * gid], y = W4[2 * gid + 1];
    bf16x8 o;
    o[0] = (short)f2bf(x[0]); o[1] = (short)f2bf(x[1]);
    o[2] = (short)f2bf(x[2]); o[3] = (short)f2bf(x[3]);
    o[4] = (short)f2bf(y[0]); o[5] = (short)f2bf(y[1]);
    o[6] = (short)f2bf(y[2]); o[7] = (short)f2bf(y[3]);
    Wb8[gid] = o;
  }
}

__global__ void build_masks(const int* __restrict__ cand, float* __restrict__ keep,
                            int* __restrict__ cf, int* __restrict__ cn,
                            float* __restrict__ out, int* __restrict__ bar) {
  int gid = blockIdx.x * 256 + threadIdx.x;
  if (gid < NF * NN) keep[gid] = 1.0f;
  if (gid < NB) {
    cf[gid] = cand[3 * gid];
    cn[gid] = cand[3 * gid + 1] * 64 + cand[3 * gid + 2];
    out[gid] = 0.f;
  }
  if (gid < NGRP * NF) bar[gid] = 0;
}

__global__ void scatter_sel(const int* __restrict__ sel, float* __restrict__ keep) {
  int s = threadIdx.x;  // NS threads
  int sf = sel[3 * s], sn = sel[3 * s + 1] * 64 + sel[3 * s + 2];
  keep[sf * NN + sn] = 0.0f;
}

// ---------------------------------------------------------------------------
// group barrier: 24 blocks sharing an M-tile row arrive+spin on one counter.
// ---------------------------------------------------------------------------
__device__ __forceinline__ void group_barrier(int* cnt, int t) {
  __syncthreads();
  if (t == 0) {
    __builtin_amdgcn_fence(__ATOMIC_RELEASE, "agent");
    __hip_atomic_fetch_add(cnt, 1, __ATOMIC_RELAXED, __HIP_MEMORY_SCOPE_AGENT);
    while (__hip_atomic_load(cnt, __ATOMIC_RELAXED, __HIP_MEMORY_SCOPE_AGENT) < GRPBLKS)
      __builtin_amdgcn_s_sleep(2);
    __builtin_amdgcn_fence(__ATOMIC_ACQUIRE, "agent");
  }
  __syncthreads();
}

// ---------------------------------------------------------------------------
// persistent kernel: frame0 + all 31 frame-GEMMs in one dispatch.
// v3: 5-buffer ring / 4 slices in flight -> DMA target at slice s was last
//     read at slice s-1, so the DMA issues right after the single arrival
//     barrier (overlapping this slice's ds_read+MFMA). The per-slice
//     lgkmcnt(0)+second-barrier of v2 is gone. setprio(1) wraps the MFMAs.
// ---------------------------------------------------------------------------
__launch_bounds__(512, 2)
__global__ void persist_kernel(const unsigned short* __restrict__ Wb,
                               const float* __restrict__ biases,
                               const float* __restrict__ keep,
                               const int* __restrict__ cf, const int* __restrict__ cn,
                               unsigned short* __restrict__ errA,
                               unsigned short* __restrict__ errB,
                               float* __restrict__ out, int* __restrict__ bar) {
  __shared__ __align__(16) unsigned char sA[NBUF][BM * BK * 2];   // 5 x 16 KB
  __shared__ __align__(16) unsigned char sB[NBUF][BN * BK * 2];   // 5 x 12 KB

  const int t = threadIdx.x;
  const int l = t & 63, w = t >> 6;            // 8 waves
  const int wm = w >> 1, wn = w & 1;           // compute: 4x2 waves, 32x48 each
  const int id = blockIdx.x;
  const int g = id & 7;                        // group == M-tile (XCD-local)
  const int mBase = g * BM;
  const int nBase = (id >> 3) * BN;

  // ---- frame 0: err0 = mask(bias0), rowsum -> atomicAdd out ----
  {
    const int row = mBase + (t >> 2);
    const int c0 = nBase + (t & 3) * 24;
    const int kn = (cf[row] == 0) ? cn[row] : -1;
    float sum = 0.f;
    for (int j = 0; j < 24; ++j) {
      const int col = c0 + j;
      float v = biases[col] * keep[col];
      if (col == kn) v = 0.f;
      errA[row * NN + col] = f2bf(v);
      sum += v;
    }
    sum += __shfl_xor(sum, 1, 64);
    sum += __shfl_xor(sum, 2, 64);
    if ((t & 3) == 0) atomicAdd(&out[row], sum);
  }
  group_barrier(&bar[g * NF + 0], t);

  // staging geometry: one issue = 8 rows x 64 cols (1 KB per wave);
  // lane l -> row +(l>>3), fetches swizzled chunk (l&7)^(row&7), lands at l*16
  const int sRow = l >> 3;
  const int sCk = (l & 7) ^ sRow;
  const bool aRole = (w < 4);
  const int rw = aRole ? w : (w - 4);
  const int ldsOff = aRole ? (rw * 32 * 128 + l * 16) : (rw * 24 * 128 + l * 16);
  const int gRowOff = aRole ? ((mBase + rw * 32 + sRow) * NN + sCk * 8)
                            : ((nBase + rw * 24 + sRow) * NN + sCk * 8);

  // fragment read geometry (16x16x32 bf16): lane holds [m=l&15][k=(l>>4)*8+j]
  const int fl = l & 15, q = l >> 4;
  const int fragB0 = (q ^ (fl & 7)) * 16;  // swizzled byte offset, kk=0; kk=32 -> ^64

  for (int f = 1; f < NF; ++f) {
    const unsigned short* Ain = (f & 1) ? errA : errB;
    unsigned short* errOut = (f & 1) ? errB : errA;
    const unsigned short* gSrc =
        (aRole ? Ain : Wb + (size_t)(f - 1) * NN * NN) + gRowOff;
    const float* biasf = biases + f * NN;
    const float* keepf = keep + f * NN;

    f32x4 acc[2][3];
#pragma unroll
    for (int r = 0; r < 2; ++r)
#pragma unroll
      for (int c = 0; c < 3; ++c) acc[r][c] = (f32x4){0.f, 0.f, 0.f, 0.f};

    // prologue: fill the pipeline (slices 0..3 -> buffers 0..3)
#pragma unroll
    for (int p = 0; p < DEPTH; ++p) {
      const unsigned short* gp = gSrc + p * BK;
      if (aRole) {
        unsigned char* la = &sA[p][ldsOff];
#pragma unroll
        for (int c = 0; c < 4; ++c) async16(gp + c * 8 * NN, la + c * 8 * 128);
      } else {
        unsigned char* lb = &sB[p][ldsOff];
#pragma unroll
        for (int c = 0; c < 3; ++c) async16(gp + c * 8 * NN, lb + c * 8 * 128);
      }
    }

    int rbuf = 0, wbuf = DEPTH;   // read slice s from rbuf; DMA slice s+4 into wbuf
    for (int s = 0; s < KSLICES; ++s) {
      const int ahead = KSLICES - 1 - s;   // uniform across block
      if (ahead >= 3) { if (aRole) WAITV(12); else WAITV(9); }
      else if (ahead == 2) { if (aRole) WAITV(8); else WAITV(6); }
      else if (ahead == 1) { if (aRole) WAITV(4); else WAITV(3); }
      else { WAITV(0); }
      asm volatile("s_barrier" ::: "memory");
      // wbuf == (s+4)%5 == (s-1)%5: last read at slice s-1, all waves past
      // that read (their MFMAs consumed it) before this barrier -> safe.
      if (s + DEPTH < KSLICES) {
        const unsigned short* gp = gSrc + (s + DEPTH) * BK;
        if (aRole) {
          unsigned char* la = &sA[wbuf][ldsOff];
#pragma unroll
          for (int c = 0; c < 4; ++c) async16(gp + c * 8 * NN, la + c * 8 * 128);
        } else {
          unsigned char* lb = &sB[wbuf][ldsOff];
#pragma unroll
          for (int c = 0; c < 3; ++c) async16(gp + c * 8 * NN, lb + c * 8 * 128);
        }
      }

      const unsigned char* pa = &sA[rbuf][(wm * 32 + fl) * 128];
      const unsigned char* pb = &sB[rbuf][(wn * 48 + fl) * 128];
      __builtin_amdgcn_s_setprio(1);
#pragma unroll
      for (int h = 0; h < 2; ++h) {
        const int cb = fragB0 ^ (h * 64);
        bf16x8 aF[2], bF[3];
#pragma unroll
        for (int r = 0; r < 2; ++r) aF[r] = *(const bf16x8*)(pa + r * 2048 + cb);
#pragma unroll
        for (int c = 0; c < 3; ++c) bF[c] = *(const bf16x8*)(pb + c * 2048 + cb);
#pragma unroll
        for (int r = 0; r < 2; ++r)
#pragma unroll
          for (int c = 0; c < 3; ++c)
            acc[r][c] = __builtin_amdgcn_mfma_f32_16x16x32_bf16(aF[r], bF[c], acc[r][c], 0, 0, 0);
      }
      __builtin_amdgcn_s_setprio(0);
      rbuf = (rbuf == NBUF - 1) ? 0 : rbuf + 1;
      wbuf = (wbuf == NBUF - 1) ? 0 : wbuf + 1;
    }

    // epilogue: C/D layout col=lane&15, row=(lane>>4)*4+reg
#pragma unroll
    for (int r = 0; r < 2; ++r) {
      float rs[4] = {0.f, 0.f, 0.f, 0.f};
      const int rowB = mBase + wm * 32 + r * 16 + q * 4;
#pragma unroll
      for (int c = 0; c < 3; ++c) {
        const int col = nBase + wn * 48 + c * 16 + fl;
        const float kv = keepf[col], bv = biasf[col];
#pragma unroll
        for (int i = 0; i < 4; ++i) {
          const int row = rowB + i;
          float v = (acc[r][c][i] + bv) * kv;
          if (cf[row] == f && cn[row] == col) v = 0.f;
          errOut[row * NN + col] = f2bf(v);
          rs[i] += v;
        }
      }
#pragma unroll
      for (int m = 1; m < 16; m <<= 1) {
#pragma unroll
        for (int i = 0; i < 4; ++i) rs[i] += __shfl_xor(rs[i], m, 64);
      }
      if (fl == 0) {
#pragma unroll
        for (int i = 0; i < 4; ++i) atomicAdd(&out[rowB + i], rs[i]);
      }
    }

    group_barrier(&bar[g * NF + f], t);
  }
}

// ---------------------------------------------------------------------------
extern "C" void kernel_launch(void* const* d_in, const int* in_sizes, int n_in,
                              void* d_out, int out_size, void* d_ws, size_t ws_size,
                              hipStream_t stream) {
  (void)in_sizes; (void)n_in; (void)out_size; (void)ws_size;
  const float* W = (const float*)d_in[0];
  const float* biases = (const float*)d_in[1];
  const int* sel = (const int*)d_in[2];
  const int* cand = (const int*)d_in[3];
  float* out = (float*)d_out;
  char* ws = (char*)d_ws;

  size_t off = 0;
  unsigned short* Wb = (unsigned short*)(ws + off); off += (size_t)31 * NN * NN * 2;
  float* keep = (float*)(ws + off); off += (size_t)NF * NN * 4;
  int* cf = (int*)(ws + off); off += NB * 4;
  int* cn = (int*)(ws + off); off += NB * 4;
  int* bar = (int*)(ws + off); off += NGRP * NF * 4;
  off = (off + 255) & ~(size_t)255;
  unsigned short* errA = (unsigned short*)(ws + off); off += (size_t)NB * NN * 2;
  unsigned short* errB = (unsigned short*)(ws + off);

  convert_w<<<4096, 256, 0, stream>>>((const f32x4*)W, (bf16x8*)Wb);
  build_masks<<<(NF * NN + 255) / 256, 256, 0, stream>>>(cand, keep, cf, cn, out, bar);
  scatter_sel<<<1, NS, 0, stream>>>(sel, keep);

  const unsigned short* WbC = Wb;
  void* kargs[] = {(void*)&WbC, (void*)&biases, (void*)&keep, (void*)&cf, (void*)&cn,
                   (void*)&errA, (void*)&errB, (void*)&out, (void*)&bar};
  hipError_t e = hipLaunchCooperativeKernel(
      reinterpret_cast<void*>(persist_kernel), dim3(NGRP * GRPBLKS), dim3(512),
      kargs, 0, stream);
  if (e != hipSuccess) {
    // graph-capture fallback: 192 blocks at 1 block/CU on 256 CUs are
    // physically co-resident; group barrier only spans 24 blocks.
    persist_kernel<<<NGRP * GRPBLKS, 512, 0, stream>>>(Wb, biases, keep, cf, cn,
                                                       errA, errB, out, bar);
  }
}